// Round 1
// baseline (10110.409 us; speedup 1.0000x reference)
//
#include <hip/hip_runtime.h>
#include <hip/hip_bf16.h>
#include <math.h>

// Problem constants
#define BB 16
#define SS 1024
#define EE 256
#define HH 256
#define G4 1024      // 4*H
#define NW 64        // workgroups per direction in recurrent kernel
#define JC 4         // hidden columns per group (HH/NW)

// Workspace layout (bytes)
static constexpr size_t FLAGS_OFF = 0;                         // 2*1024 uint (8 KB used, 16 KB reserved)
static constexpr size_t HBUF_OFF  = 16384;                     // [2 par][2 dir][16 b][256 j] f32 = 64 KB
static constexpr size_t LEN_OFF   = 81920;                     // 16 int
static constexpr size_t HIST_OFF  = 131072;                    // [2 dir][16 b][1024 t][256 j] f32 = 32 MB
static constexpr size_t XPF_OFF   = HIST_OFF + (size_t)2*BB*SS*HH*4;   // 64 MB
static constexpr size_t XPB_OFF   = XPF_OFF + (size_t)BB*SS*G4*4;      // 64 MB
// total = XPB_OFF + 64MB ~= 160.1 MiB

// ---------------- K1: lengths from mask (format auto-detect) ----------------
__global__ void len_kernel(const void* __restrict__ mask, int* __restrict__ lengths)
{
    const int b = blockIdx.x;
    const int t = threadIdx.x;
    const unsigned char* mb = (const unsigned char*)mask;
    // mask rows are prefixes with length >= 512, so element 1 is true.
    // byte-format => mb[1] == 1 ; int32/float32-format => mb[1] == 0.
    const bool byteFmt = (mb[1] != 0);
    int cnt = 0;
    if (byteFmt) {
        const unsigned char* row = mb + (size_t)b * SS;
        for (int i = t; i < SS; i += 256) cnt += (row[i] != 0);
    } else {
        const int* row = ((const int*)mask) + (size_t)b * SS;
        for (int i = t; i < SS; i += 256) cnt += (row[i] != 0);
    }
    __shared__ int sred[256];
    sred[t] = cnt;
    __syncthreads();
    for (int s = 128; s > 0; s >>= 1) { if (t < s) sred[t] += sred[t + s]; __syncthreads(); }
    if (t == 0) lengths[b] = sred[0];
}

// ---------------- K2: fused embed-gather + input-projection GEMM ----------------
// C[token(16384), n(2048)] = emb[x[token]] @ [W_ih_f | W_ih_b]^T + bias,
// written to xpF/xpB in [b][s][1024] layout.
#define GB_BM 128
#define GB_BN 128
#define GB_BK 32
__global__ __launch_bounds__(256) void xp_gemm(
    const int* __restrict__ x, const float* __restrict__ emb,
    const float* __restrict__ wf, const float* __restrict__ bf,
    const float* __restrict__ wb, const float* __restrict__ bb,
    float* __restrict__ xpF, float* __restrict__ xpB)
{
    __shared__ float As[GB_BK][GB_BM + 4];
    __shared__ float Bs[GB_BK][GB_BN + 4];
    __shared__ int idxs[GB_BM];

    const int t = threadIdx.x;
    const int tokBase = blockIdx.x * GB_BM;
    const int nBase   = blockIdx.y * GB_BN;
    const int nOff    = nBase & (G4 - 1);
    const float* Wp   = (nBase < G4) ? wf : wb;

    if (t < GB_BM) idxs[t] = x[tokBase + t];
    __syncthreads();

    const int tx = t & 15, ty = t >> 4;
    float acc[8][8];
#pragma unroll
    for (int i = 0; i < 8; i++)
#pragma unroll
        for (int j = 0; j < 8; j++) acc[i][j] = 0.f;

    for (int k0 = 0; k0 < EE; k0 += GB_BK) {
#pragma unroll
        for (int it = 0; it < 4; ++it) {
            const int flat = t + it * 256;       // 0..1023
            const int m  = flat & 127;
            const int kq = flat >> 7;            // 0..7
            const int idx = idxs[m];
            const float4 av = *(const float4*)(emb + (size_t)idx * EE + k0 + kq * 4);
            As[kq * 4 + 0][m] = av.x; As[kq * 4 + 1][m] = av.y;
            As[kq * 4 + 2][m] = av.z; As[kq * 4 + 3][m] = av.w;
            const float4 bv = *(const float4*)(Wp + (size_t)(nOff + m) * EE + k0 + kq * 4);
            Bs[kq * 4 + 0][m] = bv.x; Bs[kq * 4 + 1][m] = bv.y;
            Bs[kq * 4 + 2][m] = bv.z; Bs[kq * 4 + 3][m] = bv.w;
        }
        __syncthreads();
#pragma unroll
        for (int k = 0; k < GB_BK; k++) {
            const float4 a0 = *(const float4*)&As[k][ty * 8];
            const float4 a1 = *(const float4*)&As[k][ty * 8 + 4];
            const float4 b0 = *(const float4*)&Bs[k][tx * 8];
            const float4 b1 = *(const float4*)&Bs[k][tx * 8 + 4];
            const float a_[8] = {a0.x, a0.y, a0.z, a0.w, a1.x, a1.y, a1.z, a1.w};
            const float b_[8] = {b0.x, b0.y, b0.z, b0.w, b1.x, b1.y, b1.z, b1.w};
#pragma unroll
            for (int i = 0; i < 8; i++)
#pragma unroll
                for (int j = 0; j < 8; j++) acc[i][j] = fmaf(a_[i], b_[j], acc[i][j]);
        }
        __syncthreads();
    }

    const float* biasP = (nBase < G4) ? bf : bb;
    float bj[8];
#pragma unroll
    for (int j = 0; j < 8; j++) bj[j] = biasP[nOff + tx * 8 + j];
    float* outP = (nBase < G4) ? xpF : xpB;
#pragma unroll
    for (int i = 0; i < 8; i++) {
        const int token = tokBase + ty * 8 + i;
        float* row = outP + (size_t)token * G4 + nOff + tx * 8;
        float4 v0, v1;
        v0.x = acc[i][0] + bj[0]; v0.y = acc[i][1] + bj[1];
        v0.z = acc[i][2] + bj[2]; v0.w = acc[i][3] + bj[3];
        v1.x = acc[i][4] + bj[4]; v1.y = acc[i][5] + bj[5];
        v1.z = acc[i][6] + bj[6]; v1.w = acc[i][7] + bj[7];
        *(float4*)row = v0;
        *(float4*)(row + 4) = v1;
    }
}

// ---------------- K3: persistent bidirectional LSTM ----------------
// Grid = 128 blocks (dir = bid&1, group g = bid>>1, 64 groups/dir).
// Group owns hidden cols [g*4, g*4+4) => 16 gate rows; W_hh slice cached in registers.
// Per-step device-scope counter barrier per direction; h double-buffered in global.
__global__ __launch_bounds__(256) void lstm_kernel(
    const float* __restrict__ xpF, const float* __restrict__ xpB,
    const float* __restrict__ whhF, const float* __restrict__ whhB,
    const int* __restrict__ lengths,
    float* __restrict__ hbuf,        // [2 par][2 dir][16][256]
    float* __restrict__ hist,        // [2 dir][16][1024][256]
    unsigned int* __restrict__ cnt)  // [2 dir][1024]
{
    const int bid = blockIdx.x;
    const int dir = bid & 1;
    const int g   = bid >> 1;
    const int t   = threadIdx.x;
    const float* xp  = dir ? xpB : xpF;
    const float* whh = dir ? whhB : whhF;
    unsigned int* mycnt = cnt + dir * SS;

    __shared__ float hsh[16][264];       // h state, padded
    __shared__ float part_s[4][16][17];  // [ks][r][b] partial dots
    __shared__ float gates_s[16][17];    // [r][b] activated gates
    __shared__ int   len_s[16];

    // dot roles: wave ks handles k in [ks*64, ks*64+64)
    const int ks   = t >> 6;
    const int lane = t & 63;
    const int bg   = lane >> 4;          // batch quad 0..3
    const int r    = lane & 15;          // local gate row 0..15
    const int grow = (r >> 2) * HH + g * JC + (r & 3);

    float4 Wc[16];
    {
        const float4* wp = (const float4*)(whh + (size_t)grow * HH + ks * 64);
#pragma unroll
        for (int q = 0; q < 16; q++) Wc[q] = wp[q];
    }
    if (t < 16) len_s[t] = lengths[t];

    // update role (t < 64): one (b, jj) cell
    const int b_u = t >> 2, jj_u = t & 3;
    float c_reg = 0.f, h_reg = 0.f;
    // combine role: (rc, bc)
    const int rc = t >> 4, bc = t & 15;
    const int growc = (rc >> 2) * HH + g * JC + (rc & 3);
    const int gtypec = rc >> 2;
    __syncthreads();

    for (int n = 0; n < SS; ++n) {
        const int ts    = dir ? (SS - 1 - n) : n;
        const int par_r = (n + 1) & 1;
        const int par_w = n & 1;

        // prefetch this step's xp value for the combine role (latency hidden)
        const float xpv = xp[((size_t)bc * SS + ts) * G4 + growc];

        // stage h(prev) -> LDS, coalesced 64B/thread
        {
            const float4* p = (const float4*)(hbuf + par_r * 8192 + dir * 4096 + t * 16);
            const float4 h0 = p[0], h1 = p[1], h2 = p[2], h3 = p[3];
            float* dst = &hsh[t >> 4][(t & 15) * 16];
            ((float4*)dst)[0] = h0; ((float4*)dst)[1] = h1;
            ((float4*)dst)[2] = h2; ((float4*)dst)[3] = h3;
        }
        __syncthreads();

        // partial dots: W_hh (regs) x h (LDS)
        float acc0 = 0.f, acc1 = 0.f, acc2 = 0.f, acc3 = 0.f;
#pragma unroll
        for (int q = 0; q < 16; q++) {
            const float4 w4 = Wc[q];
            const int kk = ks * 64 + q * 4;
            const float4 h0 = *(const float4*)&hsh[bg * 4 + 0][kk];
            const float4 h1 = *(const float4*)&hsh[bg * 4 + 1][kk];
            const float4 h2 = *(const float4*)&hsh[bg * 4 + 2][kk];
            const float4 h3 = *(const float4*)&hsh[bg * 4 + 3][kk];
            acc0 = fmaf(w4.x, h0.x, acc0); acc0 = fmaf(w4.y, h0.y, acc0);
            acc0 = fmaf(w4.z, h0.z, acc0); acc0 = fmaf(w4.w, h0.w, acc0);
            acc1 = fmaf(w4.x, h1.x, acc1); acc1 = fmaf(w4.y, h1.y, acc1);
            acc1 = fmaf(w4.z, h1.z, acc1); acc1 = fmaf(w4.w, h1.w, acc1);
            acc2 = fmaf(w4.x, h2.x, acc2); acc2 = fmaf(w4.y, h2.y, acc2);
            acc2 = fmaf(w4.z, h2.z, acc2); acc2 = fmaf(w4.w, h2.w, acc2);
            acc3 = fmaf(w4.x, h3.x, acc3); acc3 = fmaf(w4.y, h3.y, acc3);
            acc3 = fmaf(w4.z, h3.z, acc3); acc3 = fmaf(w4.w, h3.w, acc3);
        }
        part_s[ks][r][bg * 4 + 0] = acc0;
        part_s[ks][r][bg * 4 + 1] = acc1;
        part_s[ks][r][bg * 4 + 2] = acc2;
        part_s[ks][r][bg * 4 + 3] = acc3;
        __syncthreads();

        // combine + activation (all 256 threads, 1 transcendental each)
        {
            const float gv = part_s[0][rc][bc] + part_s[1][rc][bc]
                           + part_s[2][rc][bc] + part_s[3][rc][bc] + xpv;
            const float av = (gtypec == 2) ? tanhf(gv) : 1.f / (1.f + expf(-gv));
            gates_s[rc][bc] = av;
        }
        __syncthreads();

        // state update (64 threads)
        if (t < 64) {
            const float iv = gates_s[0 + jj_u][b_u];
            const float fv = gates_s[4 + jj_u][b_u];
            const float gg = gates_s[8 + jj_u][b_u];
            const float ov = gates_s[12 + jj_u][b_u];
            const float cn = fmaf(fv, c_reg, iv * gg);
            const float hn = ov * tanhf(cn);
            const bool m = (ts < len_s[b_u]);
            if (m) { c_reg = cn; h_reg = hn; }
            hbuf[par_w * 8192 + dir * 4096 + b_u * HH + g * JC + jj_u] = h_reg;
            hist[(((size_t)dir * BB + b_u) * SS + ts) * HH + g * JC + jj_u] = m ? h_reg : 0.f;
        }
        __syncthreads();

        // per-direction device barrier for this step
        if (t == 0) {
            __hip_atomic_fetch_add(mycnt + n, 1u, __ATOMIC_RELEASE, __HIP_MEMORY_SCOPE_AGENT);
            while (__hip_atomic_load(mycnt + n, __ATOMIC_ACQUIRE, __HIP_MEMORY_SCOPE_AGENT) < (unsigned)NW)
                __builtin_amdgcn_s_sleep(2);
        }
        __syncthreads();
    }
}

// ---------------- K4: gate dot + sigmoid + per-row exact top-k ranks ----------------
__global__ void out_kernel(const float* __restrict__ hist, const float* __restrict__ zw,
                           const float* __restrict__ zb, const int* __restrict__ lengths,
                           float* __restrict__ zout)
{
    const int b = blockIdx.x;
    const int t = threadIdx.x;
    __shared__ float probs[SS];
    __shared__ float zwsh[2 * HH];
    __shared__ int lsh;
    zwsh[t] = zw[t];
    zwsh[HH + t] = zw[HH + t];
    if (t == 0) lsh = lengths[b];
    __syncthreads();
    const int len = lsh;
    const float zbv = zb[0];

    for (int s = t; s < SS; s += 256) {
        const float4* hf  = (const float4*)(hist + ((size_t)b * SS + s) * HH);
        const float4* hb2 = (const float4*)(hist + (((size_t)BB + b) * SS + s) * HH);
        const float4* z0 = (const float4*)zwsh;
        const float4* z1 = (const float4*)(zwsh + HH);
        float acc = 0.f;
#pragma unroll 8
        for (int q = 0; q < HH / 4; q++) {
            const float4 h = hf[q], zv = z0[q];
            acc = fmaf(h.x, zv.x, acc); acc = fmaf(h.y, zv.y, acc);
            acc = fmaf(h.z, zv.z, acc); acc = fmaf(h.w, zv.w, acc);
        }
#pragma unroll 8
        for (int q = 0; q < HH / 4; q++) {
            const float4 h = hb2[q], zv = z1[q];
            acc = fmaf(h.x, zv.x, acc); acc = fmaf(h.y, zv.y, acc);
            acc = fmaf(h.z, zv.z, acc); acc = fmaf(h.w, zv.w, acc);
        }
        const float d = acc + zbv;
        probs[s] = (s < len) ? 1.f / (1.f + expf(-d)) : 0.f;
    }
    __syncthreads();

    // jnp.round is half-to-even; 0.1f*len lands exactly on x.5 for len%10==5 -> rintf
    const int kb = (int)rintf(0.1f * (float)len);
    for (int s = t; s < SS; s += 256) {
        const float p = probs[s];
        int rank = 0;
        for (int j = 0; j < SS; j++) {
            const float pj = probs[j];
            rank += (pj > p) ? 1 : 0;
            rank += ((pj == p) && (j < s)) ? 1 : 0;
        }
        zout[b * SS + s] = (s < len && rank < kb) ? 1.f : 0.f;
    }
}

// ---------------- launch ----------------
extern "C" void kernel_launch(void* const* d_in, const int* in_sizes, int n_in,
                              void* d_out, int out_size, void* d_ws, size_t ws_size,
                              hipStream_t stream)
{
    (void)in_sizes; (void)n_in; (void)out_size; (void)ws_size;
    const int*   x    = (const int*)d_in[0];
    const void*  mask = d_in[1];
    const float* emb  = (const float*)d_in[2];
    const float* wihf = (const float*)d_in[3];
    const float* whhf = (const float*)d_in[4];
    const float* bf   = (const float*)d_in[5];
    const float* wihb = (const float*)d_in[6];
    const float* whhb = (const float*)d_in[7];
    const float* bb   = (const float*)d_in[8];
    const float* zw   = (const float*)d_in[9];
    const float* zb   = (const float*)d_in[10];
    float* zout = (float*)d_out;

    char* ws = (char*)d_ws;
    unsigned int* cnt  = (unsigned int*)(ws + FLAGS_OFF);
    float* hbuf        = (float*)(ws + HBUF_OFF);
    int*   lengths     = (int*)(ws + LEN_OFF);
    float* hist        = (float*)(ws + HIST_OFF);
    float* xpF         = (float*)(ws + XPF_OFF);
    float* xpB         = (float*)(ws + XPB_OFF);

    // zero barrier counters + h double-buffer (ws is poisoned 0xAA each call)
    hipMemsetAsync(ws, 0, HBUF_OFF + (size_t)2 * 2 * BB * HH * 4, stream);

    len_kernel<<<BB, 256, 0, stream>>>(mask, lengths);
    xp_gemm<<<dim3((BB * SS) / GB_BM, (2 * G4) / GB_BN), 256, 0, stream>>>(
        x, emb, wihf, bf, wihb, bb, xpF, xpB);
    lstm_kernel<<<2 * NW, 256, 0, stream>>>(xpF, xpB, whhf, whhb, lengths, hbuf, hist, cnt);
    out_kernel<<<BB, 256, 0, stream>>>(hist, zw, zb, lengths, zout);
}

// Round 5
// 4265.705 us; speedup vs baseline: 2.3702x; 2.3702x over previous
//
#include <hip/hip_runtime.h>
#include <hip/hip_bf16.h>
#include <math.h>

// Problem constants
#define BB 16
#define SS 1024
#define EE 256
#define HH 256
#define G4 1024      // 4*H

// LSTM decomposition: 8 clusters = (2 dir) x (4 sample-groups of 4 samples).
// Each cluster = 8 WGs, one per 32-hidden-col block (128 gate rows each).
// Sync is fence-free relaxed-atomic (coherence-point resident) within cluster.
#define NSG 4        // sample groups
#define SGS 4        // samples per group
#define NCB 8        // col blocks
#define CBC 32       // cols per block
#define LROWS 128    // gate rows per WG (4 gates * 32 cols)
#define LTHR 512     // threads per lstm WG
#define HB_PAR 8192  // hbuf parity stride in floats (8 clusters * 1024)

// Workspace layout (bytes)
static constexpr size_t FLAGS_OFF = 0;                         // [8 clusters][8 cb] x 64B pad = 4 KB
static constexpr size_t HBUF_OFF  = 16384;                     // [2 par][8 cluster][1024] f32 = 64 KB -> ends at 81920
static constexpr size_t LEN_OFF   = 81920;                     // 16 int
static constexpr size_t HIST_OFF  = 131072;                    // [2 dir][16 b][1024 t][256 j] f32 = 32 MB
static constexpr size_t XPF_OFF   = HIST_OFF + (size_t)2*BB*SS*HH*4;   // 64 MB
static constexpr size_t XPB_OFF   = XPF_OFF + (size_t)BB*SS*G4*4;      // 64 MB

// ---------------- K1: lengths from mask (format auto-detect) ----------------
__global__ void len_kernel(const void* __restrict__ mask, int* __restrict__ lengths)
{
    const int b = blockIdx.x;
    const int t = threadIdx.x;
    const unsigned char* mb = (const unsigned char*)mask;
    const bool byteFmt = (mb[1] != 0);   // lengths >= 512 so element 1 is always true
    int cnt = 0;
    if (byteFmt) {
        const unsigned char* row = mb + (size_t)b * SS;
        for (int i = t; i < SS; i += 256) cnt += (row[i] != 0);
    } else {
        const int* row = ((const int*)mask) + (size_t)b * SS;
        for (int i = t; i < SS; i += 256) cnt += (row[i] != 0);
    }
    __shared__ int sred[256];
    sred[t] = cnt;
    __syncthreads();
    for (int s = 128; s > 0; s >>= 1) { if (t < s) sred[t] += sred[t + s]; __syncthreads(); }
    if (t == 0) lengths[b] = sred[0];
}

// ---------------- K2: fused embed-gather + input-projection GEMM ----------------
#define GB_BM 128
#define GB_BN 128
#define GB_BK 32
__global__ __launch_bounds__(256) void xp_gemm(
    const int* __restrict__ x, const float* __restrict__ emb,
    const float* __restrict__ wf, const float* __restrict__ bf,
    const float* __restrict__ wb, const float* __restrict__ bb,
    float* __restrict__ xpF, float* __restrict__ xpB)
{
    __shared__ float As[GB_BK][GB_BM + 4];
    __shared__ float Bs[GB_BK][GB_BN + 4];
    __shared__ int idxs[GB_BM];

    const int t = threadIdx.x;
    const int tokBase = blockIdx.x * GB_BM;
    const int nBase   = blockIdx.y * GB_BN;
    const int nOff    = nBase & (G4 - 1);
    const float* Wp   = (nBase < G4) ? wf : wb;

    if (t < GB_BM) idxs[t] = x[tokBase + t];
    __syncthreads();

    const int tx = t & 15, ty = t >> 4;
    float acc[8][8];
#pragma unroll
    for (int i = 0; i < 8; i++)
#pragma unroll
        for (int j = 0; j < 8; j++) acc[i][j] = 0.f;

    for (int k0 = 0; k0 < EE; k0 += GB_BK) {
#pragma unroll
        for (int it = 0; it < 4; ++it) {
            const int flat = t + it * 256;
            const int m  = flat & 127;
            const int kq = flat >> 7;
            const int idx = idxs[m];
            const float4 av = *(const float4*)(emb + (size_t)idx * EE + k0 + kq * 4);
            As[kq * 4 + 0][m] = av.x; As[kq * 4 + 1][m] = av.y;
            As[kq * 4 + 2][m] = av.z; As[kq * 4 + 3][m] = av.w;
            const float4 bv = *(const float4*)(Wp + (size_t)(nOff + m) * EE + k0 + kq * 4);
            Bs[kq * 4 + 0][m] = bv.x; Bs[kq * 4 + 1][m] = bv.y;
            Bs[kq * 4 + 2][m] = bv.z; Bs[kq * 4 + 3][m] = bv.w;
        }
        __syncthreads();
#pragma unroll
        for (int k = 0; k < GB_BK; k++) {
            const float4 a0 = *(const float4*)&As[k][ty * 8];
            const float4 a1 = *(const float4*)&As[k][ty * 8 + 4];
            const float4 b0 = *(const float4*)&Bs[k][tx * 8];
            const float4 b1 = *(const float4*)&Bs[k][tx * 8 + 4];
            const float a_[8] = {a0.x, a0.y, a0.z, a0.w, a1.x, a1.y, a1.z, a1.w};
            const float b_[8] = {b0.x, b0.y, b0.z, b0.w, b1.x, b1.y, b1.z, b1.w};
#pragma unroll
            for (int i = 0; i < 8; i++)
#pragma unroll
                for (int j = 0; j < 8; j++) acc[i][j] = fmaf(a_[i], b_[j], acc[i][j]);
        }
        __syncthreads();
    }

    const float* biasP = (nBase < G4) ? bf : bb;
    float bj[8];
#pragma unroll
    for (int j = 0; j < 8; j++) bj[j] = biasP[nOff + tx * 8 + j];
    float* outP = (nBase < G4) ? xpF : xpB;
#pragma unroll
    for (int i = 0; i < 8; i++) {
        const int token = tokBase + ty * 8 + i;
        float* row = outP + (size_t)token * G4 + nOff + tx * 8;
        float4 v0, v1;
        v0.x = acc[i][0] + bj[0]; v0.y = acc[i][1] + bj[1];
        v0.z = acc[i][2] + bj[2]; v0.w = acc[i][3] + bj[3];
        v1.x = acc[i][4] + bj[4]; v1.y = acc[i][5] + bj[5];
        v1.z = acc[i][6] + bj[6]; v1.w = acc[i][7] + bj[7];
        *(float4*)row = v0;
        *(float4*)(row + 4) = v1;
    }
}

// ---------------- K3: clustered bidirectional LSTM, fence-free sync ----------------
// Grid = 64 blocks. cluster = bid&7 (dir = cluster&1, sg = cluster>>1), cb = bid>>3.
// WG owns 4 samples x 32 hidden cols (128 gate rows); W_hh slice in registers
// (64 VGPR/thread). Cross-WG h exchange + epoch flags via RELAXED agent-scope
// atomics (coherence-point resident — NO acquire/release cache maintenance).
// Ordering: s_waitcnt vmcnt(0) before the per-WG epoch-flag publish.
__global__ __launch_bounds__(LTHR) void lstm_kernel(
    const float* __restrict__ xpF, const float* __restrict__ xpB,
    const float* __restrict__ whhF, const float* __restrict__ whhB,
    const int* __restrict__ lengths,
    float* __restrict__ hbuf,          // [2 par][8 cluster][8 cb][4 s][32 jl]
    float* __restrict__ hist,          // [2 dir][16 b][1024 t][256 j]
    unsigned int* __restrict__ flags)  // [8 cluster][8 cb] stride 16 u32 (64B)
{
    const int bid     = blockIdx.x;
    const int cluster = bid & 7;
    const int cb      = bid >> 3;
    const int dir     = cluster & 1;
    const int sg      = cluster >> 1;
    const int t       = threadIdx.x;

    const float* xp  = dir ? xpB : xpF;
    const float* whh = dir ? whhB : whhF;

    __shared__ float h_stage[SGS][HH];        // broadcast-read, no pad needed
    __shared__ float part_s[4 * LROWS * 5];   // [kq][r][s] stride-5 padded
    __shared__ float gates_s[LROWS * 5];      // [r][s] stride-5 padded
    __shared__ int   len_s[SGS];

    // --- roles ---
    // dot phase:   kq = t>>7 (k-quarter), r = t&127 (local gate row). Lanes at
    //              fixed kq read lane-invariant h addresses -> pure broadcast.
    const int kq = t >> 7;
    const int r  = t & 127;
    const int growD = ((r >> 5) * HH) + cb * CBC + (r & 31);  // global gate row
    // combine phase: rc = t&127 row, sc = t>>7 sample.
    const int rc = r, sc = kq;
    const int growC  = growD;
    const int gtypeC = rc >> 5;
    const int bglobC = sg * SGS + sc;
    // update phase (t<128): jl = t&31 col, su = (t>>5)&3 sample.
    const int jl = t & 31;
    const int su = (t >> 5) & 3;

    // W_hh slice -> registers: 128 rows x 64-wide k-slice per thread-quarter
    float4 Wc[16];
    {
        const float4* wp = (const float4*)(whh + (size_t)growD * HH + kq * 64);
#pragma unroll
        for (int q = 0; q < 16; q++) Wc[q] = wp[q];
    }
    if (t < SGS) len_s[t] = lengths[sg * SGS + t];

    float c_reg = 0.f, h_reg = 0.f;

    // two named pointers + ternary select (avoid runtime-indexed array -> scratch)
    const unsigned long long* hRd0 =
        (const unsigned long long*)(hbuf + 0 * HB_PAR + cluster * 1024);
    const unsigned long long* hRd1 =
        (const unsigned long long*)(hbuf + 1 * HB_PAR + cluster * 1024);
    unsigned int* myflag = flags + (cluster * 8 + cb) * 16;
    unsigned int* clflags = flags + cluster * 8 * 16;

    __syncthreads();

    for (int n = 0; n < SS; ++n) {
        const int ts    = dir ? (SS - 1 - n) : n;
        const int par_r = (n + 1) & 1;       // parity holding h_{n-1} ((n-1)&1)
        const int par_w = n & 1;

        // issue xp load early (plain cached load; HBM latency hides under poll)
        const float xpv = xp[((size_t)bglobC * SS + ts) * G4 + growC];

        // --- wait for all 8 col-block slices of h_{n-1} (epoch >= n) ---
        if (t < 64) {
            const int lane = t & 63;
            const unsigned int target = (unsigned int)n;
            for (;;) {
                unsigned int f = target;
                if (lane < NCB)
                    f = __hip_atomic_load(clflags + lane * 16, __ATOMIC_RELAXED,
                                          __HIP_MEMORY_SCOPE_AGENT);
                if (__all((int)(f >= target))) break;
                __builtin_amdgcn_s_sleep(1);
            }
        }
        __syncthreads();

        // --- stage h_{n-1} -> LDS (one u64 relaxed load per thread) ---
        {
            const unsigned long long* hRd = par_r ? hRd1 : hRd0;
            const unsigned long long v =
                __hip_atomic_load(hRd + t, __ATOMIC_RELAXED,
                                  __HIP_MEMORY_SCOPE_AGENT);
            const int f0   = 2 * t;
            const int cbS  = f0 >> 7;
            const int rem  = f0 & 127;
            const int sS   = rem >> 5;
            const int jlS  = rem & 31;
            const unsigned int lo = (unsigned int)v, hi = (unsigned int)(v >> 32);
            float* dst = &h_stage[sS][cbS * CBC + jlS];
            dst[0] = __builtin_bit_cast(float, lo);
            dst[1] = __builtin_bit_cast(float, hi);
        }
        __syncthreads();

        // --- partial dots: W (regs) x h (LDS broadcast) ---
        float a0 = 0.f, a1 = 0.f, a2 = 0.f, a3 = 0.f;
#pragma unroll
        for (int q = 0; q < 16; q++) {
            const float4 w4 = Wc[q];
            const int kk = kq * 64 + q * 4;
            const float4 h0 = *(const float4*)&h_stage[0][kk];
            const float4 h1 = *(const float4*)&h_stage[1][kk];
            const float4 h2 = *(const float4*)&h_stage[2][kk];
            const float4 h3 = *(const float4*)&h_stage[3][kk];
            a0 = fmaf(w4.x, h0.x, a0); a0 = fmaf(w4.y, h0.y, a0);
            a0 = fmaf(w4.z, h0.z, a0); a0 = fmaf(w4.w, h0.w, a0);
            a1 = fmaf(w4.x, h1.x, a1); a1 = fmaf(w4.y, h1.y, a1);
            a1 = fmaf(w4.z, h1.z, a1); a1 = fmaf(w4.w, h1.w, a1);
            a2 = fmaf(w4.x, h2.x, a2); a2 = fmaf(w4.y, h2.y, a2);
            a2 = fmaf(w4.z, h2.z, a2); a2 = fmaf(w4.w, h2.w, a2);
            a3 = fmaf(w4.x, h3.x, a3); a3 = fmaf(w4.y, h3.y, a3);
            a3 = fmaf(w4.z, h3.z, a3); a3 = fmaf(w4.w, h3.w, a3);
        }
        {
            float* p = &part_s[(kq * LROWS + r) * 5];
            p[0] = a0; p[1] = a1; p[2] = a2; p[3] = a3;
        }
        __syncthreads();

        // --- combine + activation (512 gates, 1/thread) ---
        {
            const float gv = part_s[(0 * LROWS + rc) * 5 + sc]
                           + part_s[(1 * LROWS + rc) * 5 + sc]
                           + part_s[(2 * LROWS + rc) * 5 + sc]
                           + part_s[(3 * LROWS + rc) * 5 + sc] + xpv;
            gates_s[rc * 5 + sc] = (gtypeC == 2) ? tanhf(gv)
                                                 : 1.f / (1.f + expf(-gv));
        }
        __syncthreads();

        // --- state update (128 cells) + publish ---
        if (t < 128) {
            const float iv = gates_s[(0 * CBC + jl) * 5 + su];
            const float fv = gates_s[(1 * CBC + jl) * 5 + su];
            const float gg = gates_s[(2 * CBC + jl) * 5 + su];
            const float ov = gates_s[(3 * CBC + jl) * 5 + su];
            const float cn = fmaf(fv, c_reg, iv * gg);
            const float hn = ov * tanhf(cn);
            const bool m = (ts < len_s[su]);
            if (m) { c_reg = cn; h_reg = hn; }
            // publish h slice (relaxed agent atomic -> coherence point)
            float* hw = hbuf + par_w * HB_PAR + cluster * 1024 + cb * 128 + su * 32 + jl;
            __hip_atomic_store((unsigned int*)hw,
                               __builtin_bit_cast(unsigned int, h_reg),
                               __ATOMIC_RELAXED, __HIP_MEMORY_SCOPE_AGENT);
            // history (read by out_kernel only) — nontemporal, keep L2 clean
            const int bglob = sg * SGS + su;
            __builtin_nontemporal_store(m ? h_reg : 0.f,
                hist + (((size_t)dir * BB + bglob) * SS + ts) * HH + cb * CBC + jl);
            asm volatile("s_waitcnt vmcnt(0)" ::: "memory");
        }
        __syncthreads();   // all h stores drained (per-wave vmcnt + barrier)

        if (t == 0)
            __hip_atomic_store(myflag, (unsigned int)(n + 1),
                               __ATOMIC_RELAXED, __HIP_MEMORY_SCOPE_AGENT);
    }
}

// ---------------- K4: gate dot + sigmoid + per-row exact top-k ranks ----------------
__global__ void out_kernel(const float* __restrict__ hist, const float* __restrict__ zw,
                           const float* __restrict__ zb, const int* __restrict__ lengths,
                           float* __restrict__ zout)
{
    const int b = blockIdx.x;
    const int t = threadIdx.x;
    __shared__ float probs[SS];
    __shared__ float zwsh[2 * HH];
    __shared__ int lsh;
    zwsh[t] = zw[t];
    zwsh[HH + t] = zw[HH + t];
    if (t == 0) lsh = lengths[b];
    __syncthreads();
    const int len = lsh;
    const float zbv = zb[0];

    for (int s = t; s < SS; s += 256) {
        const float4* hf  = (const float4*)(hist + ((size_t)b * SS + s) * HH);
        const float4* hb2 = (const float4*)(hist + (((size_t)BB + b) * SS + s) * HH);
        const float4* z0 = (const float4*)zwsh;
        const float4* z1 = (const float4*)(zwsh + HH);
        float acc = 0.f;
#pragma unroll 8
        for (int q = 0; q < HH / 4; q++) {
            const float4 h = hf[q], zv = z0[q];
            acc = fmaf(h.x, zv.x, acc); acc = fmaf(h.y, zv.y, acc);
            acc = fmaf(h.z, zv.z, acc); acc = fmaf(h.w, zv.w, acc);
        }
#pragma unroll 8
        for (int q = 0; q < HH / 4; q++) {
            const float4 h = hb2[q], zv = z1[q];
            acc = fmaf(h.x, zv.x, acc); acc = fmaf(h.y, zv.y, acc);
            acc = fmaf(h.z, zv.z, acc); acc = fmaf(h.w, zv.w, acc);
        }
        const float d = acc + zbv;
        probs[s] = (s < len) ? 1.f / (1.f + expf(-d)) : 0.f;
    }
    __syncthreads();

    const int kb = (int)rintf(0.1f * (float)len);  // jnp.round = half-even
    for (int s = t; s < SS; s += 256) {
        const float p = probs[s];
        int rank = 0;
        for (int j = 0; j < SS; j++) {
            const float pj = probs[j];
            rank += (pj > p) ? 1 : 0;
            rank += ((pj == p) && (j < s)) ? 1 : 0;
        }
        zout[b * SS + s] = (s < len && rank < kb) ? 1.f : 0.f;
    }
}

// ---------------- launch ----------------
extern "C" void kernel_launch(void* const* d_in, const int* in_sizes, int n_in,
                              void* d_out, int out_size, void* d_ws, size_t ws_size,
                              hipStream_t stream)
{
    (void)in_sizes; (void)n_in; (void)out_size; (void)ws_size;
    const int*   x    = (const int*)d_in[0];
    const void*  mask = d_in[1];
    const float* emb  = (const float*)d_in[2];
    const float* wihf = (const float*)d_in[3];
    const float* whhf = (const float*)d_in[4];
    const float* bf   = (const float*)d_in[5];
    const float* wihb = (const float*)d_in[6];
    const float* whhb = (const float*)d_in[7];
    const float* bb   = (const float*)d_in[8];
    const float* zw   = (const float*)d_in[9];
    const float* zb   = (const float*)d_in[10];
    float* zout = (float*)d_out;

    char* ws = (char*)d_ws;
    unsigned int* flags = (unsigned int*)(ws + FLAGS_OFF);
    float* hbuf         = (float*)(ws + HBUF_OFF);
    int*   lengths      = (int*)(ws + LEN_OFF);
    float* hist         = (float*)(ws + HIST_OFF);
    float* xpF          = (float*)(ws + XPF_OFF);
    float* xpB          = (float*)(ws + XPB_OFF);

    // zero epoch flags + BOTH parities of the h double-buffer (ws poisoned 0xAA)
    hipMemsetAsync(ws, 0, HBUF_OFF + (size_t)2 * HB_PAR * 4, stream);

    len_kernel<<<BB, 256, 0, stream>>>(mask, lengths);
    xp_gemm<<<dim3((BB * SS) / GB_BM, (2 * G4) / GB_BN), 256, 0, stream>>>(
        x, emb, wihf, bf, wihb, bb, xpF, xpB);
    lstm_kernel<<<64, LTHR, 0, stream>>>(xpF, xpB, whhf, whhb, lengths, hbuf, hist, flags);
    out_kernel<<<BB, 256, 0, stream>>>(hist, zw, zb, lengths, zout);
}

// Round 6
// 2600.541 us; speedup vs baseline: 3.8878x; 1.6403x over previous
//
#include <hip/hip_runtime.h>
#include <hip/hip_bf16.h>
#include <math.h>

// Problem constants
#define BB 16
#define SS 1024
#define EE 256
#define HH 256
#define G4 1024      // 4*H

// LSTM decomposition: 16 clusters = (2 dir) x (8 sample-groups of 2 samples).
// Each cluster = 8 WGs, one per 32-hidden-col block (128 gate rows each).
// FLAG-FREE sync: each h element is published as a self-tagged 8-byte word
// (h bits | epoch<<32) via relaxed agent-scope atomics; consumers poll the
// data words directly. No flags, no vmcnt drain, no fences on the critical path.
#define NSG 8        // sample groups
#define SGS 2        // samples per group
#define NCB 8        // col blocks
#define CBC 32       // cols per block
#define LROWS 128    // gate rows per WG (4 gates * 32 cols)
#define LTHR 512     // threads per lstm WG
#define NCLUST 16    // clusters
#define CLW 512      // tagged h words per cluster (2 samples * 256 cols)

// Workspace layout (bytes)
static constexpr size_t HBUF_OFF = 0;                          // u64[2 par][16 cluster][512] = 128 KB
static constexpr size_t HBUF_BYTES = (size_t)2 * NCLUST * CLW * 8;     // 131072
static constexpr size_t LEN_OFF  = 131072;                     // 16 int
static constexpr size_t HIST_OFF = 139264;                     // [2 dir][16 b][1024 t][256 j] f32 = 32 MB
static constexpr size_t XPF_OFF  = HIST_OFF + (size_t)2*BB*SS*HH*4;    // +64 MB
static constexpr size_t XPB_OFF  = XPF_OFF + (size_t)BB*SS*G4*4;       // +64 MB

// ---------------- K1: lengths from mask (format auto-detect) ----------------
__global__ void len_kernel(const void* __restrict__ mask, int* __restrict__ lengths)
{
    const int b = blockIdx.x;
    const int t = threadIdx.x;
    const unsigned char* mb = (const unsigned char*)mask;
    const bool byteFmt = (mb[1] != 0);   // lengths >= 512 so element 1 is always true
    int cnt = 0;
    if (byteFmt) {
        const unsigned char* row = mb + (size_t)b * SS;
        for (int i = t; i < SS; i += 256) cnt += (row[i] != 0);
    } else {
        const int* row = ((const int*)mask) + (size_t)b * SS;
        for (int i = t; i < SS; i += 256) cnt += (row[i] != 0);
    }
    __shared__ int sred[256];
    sred[t] = cnt;
    __syncthreads();
    for (int s = 128; s > 0; s >>= 1) { if (t < s) sred[t] += sred[t + s]; __syncthreads(); }
    if (t == 0) lengths[b] = sred[0];
}

// ---------------- K2: fused embed-gather + input-projection GEMM ----------------
#define GB_BM 128
#define GB_BN 128
#define GB_BK 32
__global__ __launch_bounds__(256) void xp_gemm(
    const int* __restrict__ x, const float* __restrict__ emb,
    const float* __restrict__ wf, const float* __restrict__ bf,
    const float* __restrict__ wb, const float* __restrict__ bb,
    float* __restrict__ xpF, float* __restrict__ xpB)
{
    __shared__ float As[GB_BK][GB_BM + 4];
    __shared__ float Bs[GB_BK][GB_BN + 4];
    __shared__ int idxs[GB_BM];

    const int t = threadIdx.x;
    const int tokBase = blockIdx.x * GB_BM;
    const int nBase   = blockIdx.y * GB_BN;
    const int nOff    = nBase & (G4 - 1);
    const float* Wp   = (nBase < G4) ? wf : wb;

    if (t < GB_BM) idxs[t] = x[tokBase + t];
    __syncthreads();

    const int tx = t & 15, ty = t >> 4;
    float acc[8][8];
#pragma unroll
    for (int i = 0; i < 8; i++)
#pragma unroll
        for (int j = 0; j < 8; j++) acc[i][j] = 0.f;

    for (int k0 = 0; k0 < EE; k0 += GB_BK) {
#pragma unroll
        for (int it = 0; it < 4; ++it) {
            const int flat = t + it * 256;
            const int m  = flat & 127;
            const int kq = flat >> 7;
            const int idx = idxs[m];
            const float4 av = *(const float4*)(emb + (size_t)idx * EE + k0 + kq * 4);
            As[kq * 4 + 0][m] = av.x; As[kq * 4 + 1][m] = av.y;
            As[kq * 4 + 2][m] = av.z; As[kq * 4 + 3][m] = av.w;
            const float4 bv = *(const float4*)(Wp + (size_t)(nOff + m) * EE + k0 + kq * 4);
            Bs[kq * 4 + 0][m] = bv.x; Bs[kq * 4 + 1][m] = bv.y;
            Bs[kq * 4 + 2][m] = bv.z; Bs[kq * 4 + 3][m] = bv.w;
        }
        __syncthreads();
#pragma unroll
        for (int k = 0; k < GB_BK; k++) {
            const float4 a0 = *(const float4*)&As[k][ty * 8];
            const float4 a1 = *(const float4*)&As[k][ty * 8 + 4];
            const float4 b0 = *(const float4*)&Bs[k][tx * 8];
            const float4 b1 = *(const float4*)&Bs[k][tx * 8 + 4];
            const float a_[8] = {a0.x, a0.y, a0.z, a0.w, a1.x, a1.y, a1.z, a1.w};
            const float b_[8] = {b0.x, b0.y, b0.z, b0.w, b1.x, b1.y, b1.z, b1.w};
#pragma unroll
            for (int i = 0; i < 8; i++)
#pragma unroll
                for (int j = 0; j < 8; j++) acc[i][j] = fmaf(a_[i], b_[j], acc[i][j]);
        }
        __syncthreads();
    }

    const float* biasP = (nBase < G4) ? bf : bb;
    float bj[8];
#pragma unroll
    for (int j = 0; j < 8; j++) bj[j] = biasP[nOff + tx * 8 + j];
    float* outP = (nBase < G4) ? xpF : xpB;
#pragma unroll
    for (int i = 0; i < 8; i++) {
        const int token = tokBase + ty * 8 + i;
        float* row = outP + (size_t)token * G4 + nOff + tx * 8;
        float4 v0, v1;
        v0.x = acc[i][0] + bj[0]; v0.y = acc[i][1] + bj[1];
        v0.z = acc[i][2] + bj[2]; v0.w = acc[i][3] + bj[3];
        v1.x = acc[i][4] + bj[4]; v1.y = acc[i][5] + bj[5];
        v1.z = acc[i][6] + bj[6]; v1.w = acc[i][7] + bj[7];
        *(float4*)row = v0;
        *(float4*)(row + 4) = v1;
    }
}

// ---------------- K3: clustered bi-LSTM, self-tagged flag-free sync ----------------
// Grid = 128 blocks: cluster = bid&15 (dir = cluster&1, sg = cluster>>1), cb = bid>>4.
// WG owns 2 samples x 32 hidden cols (128 gate rows); W_hh slice in registers
// (64 VGPR/thread). h published as (h_bits | (n+1)<<32) u64 relaxed atomics;
// consumers poll the tagged words directly (epoch >= n). Safety: parity reuse
// is 2 steps apart and the poll dependency chain guarantees all readers of
// epoch e finish before any writer reaches e+2.
__global__ __launch_bounds__(LTHR) void lstm_kernel(
    const float* __restrict__ xpF, const float* __restrict__ xpB,
    const float* __restrict__ whhF, const float* __restrict__ whhB,
    const int* __restrict__ lengths,
    unsigned long long* __restrict__ hbuf,  // [2 par][16 cluster][512]
    float* __restrict__ hist)               // [2 dir][16 b][1024 t][256 j]
{
    const int bid     = blockIdx.x;
    const int cluster = bid & 15;
    const int cb      = bid >> 4;
    const int dir     = cluster & 1;
    const int sg      = cluster >> 1;      // 0..7
    const int t       = threadIdx.x;

    const float* xp  = dir ? xpB : xpF;
    const float* whh = dir ? whhB : whhF;

    __shared__ float h_stage[SGS][HH];         // broadcast-read in dot phase
    __shared__ float part_s[4 * LROWS * 3];    // [kq][r][s] stride-3 padded
    __shared__ float gates_s[LROWS * 3];       // [r][s] stride-3 padded
    __shared__ int   len_s[SGS];

    // --- roles ---
    // dot phase (all 512): kq = t>>7 (k-quarter), r = t&127 (local gate row).
    const int kq = t >> 7;
    const int r  = t & 127;
    const int growD = ((r >> 5) * HH) + cb * CBC + (r & 31);  // global gate row
    // combine phase (t<256): rc = t&127 row, sc = (t>>7)&1 sample.
    const int rc = r, sc = kq & 1;
    const int gtypeC = rc >> 5;
    const int bglobC = sg * SGS + sc;
    // update phase (t<64): jl = t&31 col, su = (t>>5)&1 sample.
    const int jl = t & 31;
    const int su = (t >> 5) & 1;

    // W_hh slice -> registers: 128 rows x 64-wide k-slice per thread-quarter
    float4 Wc[16];
    {
        const float4* wp = (const float4*)(whh + (size_t)growD * HH + kq * 64);
#pragma unroll
        for (int q = 0; q < 16; q++) Wc[q] = wp[q];
    }
    if (t < SGS) len_s[t] = lengths[sg * SGS + t];

    float c_reg = 0.f, h_reg = 0.f;

    // tagged-word buffers (two named pointers; avoid runtime-indexed array)
    const unsigned long long* hRd0 = hbuf + 0 * (NCLUST * CLW) + cluster * CLW;
    const unsigned long long* hRd1 = hbuf + 1 * (NCLUST * CLW) + cluster * CLW;
    unsigned long long* hWr0 = hbuf + 0 * (NCLUST * CLW) + cluster * CLW;
    unsigned long long* hWr1 = hbuf + 1 * (NCLUST * CLW) + cluster * CLW;

    // stage-role constants: thread t owns tagged word t of the cluster
    const int sS  = (t >> 5) & 1;
    const int jS  = (t >> 6) * CBC + (t & 31);   // dest col in h_stage[sS]

    __syncthreads();

    for (int n = 0; n < SS; ++n) {
        const int ts    = dir ? (SS - 1 - n) : n;
        const int par_r = (n + 1) & 1;       // parity holding h_{n-1}
        const int par_w = n & 1;

        // prefetch this step's xp value for the combine role (issue before poll)
        float xpv = 0.f;
        if (t < 256)
            xpv = xp[((size_t)bglobC * SS + ts) * G4 + growD];

        // --- stage h_{n-1}: poll the self-tagged word until epoch >= n ---
        {
            const unsigned long long* src = (par_r ? hRd1 : hRd0) + t;
            unsigned long long v = __hip_atomic_load(src, __ATOMIC_RELAXED,
                                                     __HIP_MEMORY_SCOPE_AGENT);
            while ((unsigned int)(v >> 32) < (unsigned int)n)
                v = __hip_atomic_load(src, __ATOMIC_RELAXED,
                                      __HIP_MEMORY_SCOPE_AGENT);
            h_stage[sS][jS] = __builtin_bit_cast(float, (unsigned int)v);
        }
        __syncthreads();   // B1: h staged

        // --- partial dots: W (regs) x h (LDS broadcast) ---
        float a0 = 0.f, a1 = 0.f;
#pragma unroll
        for (int q = 0; q < 16; q++) {
            const float4 w4 = Wc[q];
            const int kk = kq * 64 + q * 4;
            const float4 h0 = *(const float4*)&h_stage[0][kk];
            const float4 h1 = *(const float4*)&h_stage[1][kk];
            a0 = fmaf(w4.x, h0.x, a0); a0 = fmaf(w4.y, h0.y, a0);
            a0 = fmaf(w4.z, h0.z, a0); a0 = fmaf(w4.w, h0.w, a0);
            a1 = fmaf(w4.x, h1.x, a1); a1 = fmaf(w4.y, h1.y, a1);
            a1 = fmaf(w4.z, h1.z, a1); a1 = fmaf(w4.w, h1.w, a1);
        }
        {
            float* p = &part_s[(kq * LROWS + r) * 3];
            p[0] = a0; p[1] = a1;
        }
        __syncthreads();   // B2: partials ready (also: h_stage reads done)

        // --- combine + activation (256 gates, t<256) ---
        if (t < 256) {
            const float gv = part_s[(0 * LROWS + rc) * 3 + sc]
                           + part_s[(1 * LROWS + rc) * 3 + sc]
                           + part_s[(2 * LROWS + rc) * 3 + sc]
                           + part_s[(3 * LROWS + rc) * 3 + sc] + xpv;
            gates_s[rc * 3 + sc] = (gtypeC == 2) ? tanhf(gv)
                                                 : 1.f / (1.f + expf(-gv));
        }
        __syncthreads();   // B3: gates ready

        // --- state update (64 cells, t<64) + tagged publish ---
        if (t < 64) {
            const float iv = gates_s[((0 << 5) | jl) * 3 + su];
            const float fv = gates_s[((1 << 5) | jl) * 3 + su];
            const float gg = gates_s[((2 << 5) | jl) * 3 + su];
            const float ov = gates_s[((3 << 5) | jl) * 3 + su];
            const float cn = fmaf(fv, c_reg, iv * gg);
            const float hn = ov * tanhf(cn);
            const bool m = (ts < len_s[su]);
            if (m) { c_reg = cn; h_reg = hn; }
            // self-tagged publish: (h bits | epoch n+1) — single 8B atomic store
            const unsigned long long val =
                (unsigned long long)__builtin_bit_cast(unsigned int, h_reg)
                | ((unsigned long long)(unsigned int)(n + 1) << 32);
            unsigned long long* dst = (par_w ? hWr1 : hWr0) + cb * 64 + su * 32 + jl;
            __hip_atomic_store(dst, val, __ATOMIC_RELAXED, __HIP_MEMORY_SCOPE_AGENT);
            // history (read by out_kernel after kernel end) — off critical path
            const int bglob = sg * SGS + su;
            __builtin_nontemporal_store(m ? h_reg : 0.f,
                hist + (((size_t)dir * BB + bglob) * SS + ts) * HH + cb * CBC + jl);
        }
        // no trailing barrier: next-step LDS writes are fenced by B1/B2/B3 pattern
    }
}

// ---------------- K4: gate dot + sigmoid + per-row exact top-k ranks ----------------
__global__ void out_kernel(const float* __restrict__ hist, const float* __restrict__ zw,
                           const float* __restrict__ zb, const int* __restrict__ lengths,
                           float* __restrict__ zout)
{
    const int b = blockIdx.x;
    const int t = threadIdx.x;
    __shared__ float probs[SS];
    __shared__ float zwsh[2 * HH];
    __shared__ int lsh;
    zwsh[t] = zw[t];
    zwsh[HH + t] = zw[HH + t];
    if (t == 0) lsh = lengths[b];
    __syncthreads();
    const int len = lsh;
    const float zbv = zb[0];

    for (int s = t; s < SS; s += 256) {
        const float4* hf  = (const float4*)(hist + ((size_t)b * SS + s) * HH);
        const float4* hb2 = (const float4*)(hist + (((size_t)BB + b) * SS + s) * HH);
        const float4* z0 = (const float4*)zwsh;
        const float4* z1 = (const float4*)(zwsh + HH);
        float acc = 0.f;
#pragma unroll 8
        for (int q = 0; q < HH / 4; q++) {
            const float4 h = hf[q], zv = z0[q];
            acc = fmaf(h.x, zv.x, acc); acc = fmaf(h.y, zv.y, acc);
            acc = fmaf(h.z, zv.z, acc); acc = fmaf(h.w, zv.w, acc);
        }
#pragma unroll 8
        for (int q = 0; q < HH / 4; q++) {
            const float4 h = hb2[q], zv = z1[q];
            acc = fmaf(h.x, zv.x, acc); acc = fmaf(h.y, zv.y, acc);
            acc = fmaf(h.z, zv.z, acc); acc = fmaf(h.w, zv.w, acc);
        }
        const float d = acc + zbv;
        probs[s] = (s < len) ? 1.f / (1.f + expf(-d)) : 0.f;
    }
    __syncthreads();

    const int kb = (int)rintf(0.1f * (float)len);  // jnp.round = half-even
    for (int s = t; s < SS; s += 256) {
        const float p = probs[s];
        int rank = 0;
        for (int j = 0; j < SS; j++) {
            const float pj = probs[j];
            rank += (pj > p) ? 1 : 0;
            rank += ((pj == p) && (j < s)) ? 1 : 0;
        }
        zout[b * SS + s] = (s < len && rank < kb) ? 1.f : 0.f;
    }
}

// ---------------- launch ----------------
extern "C" void kernel_launch(void* const* d_in, const int* in_sizes, int n_in,
                              void* d_out, int out_size, void* d_ws, size_t ws_size,
                              hipStream_t stream)
{
    (void)in_sizes; (void)n_in; (void)out_size; (void)ws_size;
    const int*   x    = (const int*)d_in[0];
    const void*  mask = d_in[1];
    const float* emb  = (const float*)d_in[2];
    const float* wihf = (const float*)d_in[3];
    const float* whhf = (const float*)d_in[4];
    const float* bf   = (const float*)d_in[5];
    const float* wihb = (const float*)d_in[6];
    const float* whhb = (const float*)d_in[7];
    const float* bb   = (const float*)d_in[8];
    const float* zw   = (const float*)d_in[9];
    const float* zb   = (const float*)d_in[10];
    float* zout = (float*)d_out;

    char* ws = (char*)d_ws;
    unsigned long long* hbuf = (unsigned long long*)(ws + HBUF_OFF);
    int*   lengths           = (int*)(ws + LEN_OFF);
    float* hist              = (float*)(ws + HIST_OFF);
    float* xpF               = (float*)(ws + XPF_OFF);
    float* xpB               = (float*)(ws + XPB_OFF);

    // zero BOTH parities of the tagged h buffer (epoch 0, h = 0). The 0xAA
    // poison would satisfy the epoch>=n poll with garbage — this memset is
    // correctness-critical.
    hipMemsetAsync(ws, 0, HBUF_BYTES, stream);

    len_kernel<<<BB, 256, 0, stream>>>(mask, lengths);
    xp_gemm<<<dim3((BB * SS) / GB_BM, (2 * G4) / GB_BN), 256, 0, stream>>>(
        x, emb, wihf, bf, wihb, bb, xpF, xpB);
    lstm_kernel<<<NCB * NCLUST, LTHR, 0, stream>>>(xpF, xpB, whhf, whhb, lengths,
                                                   hbuf, hist);
    out_kernel<<<BB, 256, 0, stream>>>(hist, zw, zb, lengths, zout);
}

// Round 7
// 1873.428 us; speedup vs baseline: 5.3967x; 1.3881x over previous
//
#include <hip/hip_runtime.h>
#include <hip/hip_bf16.h>
#include <math.h>

// Problem constants
#define BB 16
#define SS 1024
#define EE 256
#define HH 256
#define G4 1024      // 4*H

// LSTM decomposition: 32 clusters = (2 dir) x (16 samples). Each cluster =
// 8 WGs, one per 32-hidden-col block (128 gate rows x 1 sample each).
// FLAG-FREE sync: each h element is published as a self-tagged 8-byte word
// (h bits | epoch<<32) via relaxed agent-scope atomics; consumers poll the
// data words directly (with s_sleep backoff). No fences on the critical path.
#define NCB 8        // col blocks
#define CBC 32       // cols per block
#define LTHR 512     // threads per lstm WG
#define NCLUST 32    // clusters
#define CLW 256      // tagged h words per cluster (1 sample * 256 cols)

// Workspace layout (bytes)
static constexpr size_t HBUF_OFF = 0;                          // u64[2 par][32 cluster][256] = 128 KB
static constexpr size_t HBUF_BYTES = (size_t)2 * NCLUST * CLW * 8;     // 131072
static constexpr size_t LEN_OFF  = 131072;                     // 16 int
static constexpr size_t HIST_OFF = 139264;                     // [2 dir][16 b][1024 t][256 j] f32 = 32 MB
static constexpr size_t XPF_OFF  = HIST_OFF + (size_t)2*BB*SS*HH*4;    // +64 MB
static constexpr size_t XPB_OFF  = XPF_OFF + (size_t)BB*SS*G4*4;       // +64 MB

// ---------------- K1: lengths from mask (format auto-detect) ----------------
__global__ void len_kernel(const void* __restrict__ mask, int* __restrict__ lengths)
{
    const int b = blockIdx.x;
    const int t = threadIdx.x;
    const unsigned char* mb = (const unsigned char*)mask;
    const bool byteFmt = (mb[1] != 0);   // lengths >= 512 so element 1 is always true
    int cnt = 0;
    if (byteFmt) {
        const unsigned char* row = mb + (size_t)b * SS;
        for (int i = t; i < SS; i += 256) cnt += (row[i] != 0);
    } else {
        const int* row = ((const int*)mask) + (size_t)b * SS;
        for (int i = t; i < SS; i += 256) cnt += (row[i] != 0);
    }
    __shared__ int sred[256];
    sred[t] = cnt;
    __syncthreads();
    for (int s = 128; s > 0; s >>= 1) { if (t < s) sred[t] += sred[t + s]; __syncthreads(); }
    if (t == 0) lengths[b] = sred[0];
}

// ---------------- K2: fused embed-gather + input-projection GEMM ----------------
#define GB_BM 128
#define GB_BN 128
#define GB_BK 32
__global__ __launch_bounds__(256) void xp_gemm(
    const int* __restrict__ x, const float* __restrict__ emb,
    const float* __restrict__ wf, const float* __restrict__ bf,
    const float* __restrict__ wb, const float* __restrict__ bb,
    float* __restrict__ xpF, float* __restrict__ xpB)
{
    __shared__ float As[GB_BK][GB_BM + 4];
    __shared__ float Bs[GB_BK][GB_BN + 4];
    __shared__ int idxs[GB_BM];

    const int t = threadIdx.x;
    const int tokBase = blockIdx.x * GB_BM;
    const int nBase   = blockIdx.y * GB_BN;
    const int nOff    = nBase & (G4 - 1);
    const float* Wp   = (nBase < G4) ? wf : wb;

    if (t < GB_BM) idxs[t] = x[tokBase + t];
    __syncthreads();

    const int tx = t & 15, ty = t >> 4;
    float acc[8][8];
#pragma unroll
    for (int i = 0; i < 8; i++)
#pragma unroll
        for (int j = 0; j < 8; j++) acc[i][j] = 0.f;

    for (int k0 = 0; k0 < EE; k0 += GB_BK) {
#pragma unroll
        for (int it = 0; it < 4; ++it) {
            const int flat = t + it * 256;
            const int m  = flat & 127;
            const int kq = flat >> 7;
            const int idx = idxs[m];
            const float4 av = *(const float4*)(emb + (size_t)idx * EE + k0 + kq * 4);
            As[kq * 4 + 0][m] = av.x; As[kq * 4 + 1][m] = av.y;
            As[kq * 4 + 2][m] = av.z; As[kq * 4 + 3][m] = av.w;
            const float4 bv = *(const float4*)(Wp + (size_t)(nOff + m) * EE + k0 + kq * 4);
            Bs[kq * 4 + 0][m] = bv.x; Bs[kq * 4 + 1][m] = bv.y;
            Bs[kq * 4 + 2][m] = bv.z; Bs[kq * 4 + 3][m] = bv.w;
        }
        __syncthreads();
#pragma unroll
        for (int k = 0; k < GB_BK; k++) {
            const float4 a0 = *(const float4*)&As[k][ty * 8];
            const float4 a1 = *(const float4*)&As[k][ty * 8 + 4];
            const float4 b0 = *(const float4*)&Bs[k][tx * 8];
            const float4 b1 = *(const float4*)&Bs[k][tx * 8 + 4];
            const float a_[8] = {a0.x, a0.y, a0.z, a0.w, a1.x, a1.y, a1.z, a1.w};
            const float b_[8] = {b0.x, b0.y, b0.z, b0.w, b1.x, b1.y, b1.z, b1.w};
#pragma unroll
            for (int i = 0; i < 8; i++)
#pragma unroll
                for (int j = 0; j < 8; j++) acc[i][j] = fmaf(a_[i], b_[j], acc[i][j]);
        }
        __syncthreads();
    }

    const float* biasP = (nBase < G4) ? bf : bb;
    float bj[8];
#pragma unroll
    for (int j = 0; j < 8; j++) bj[j] = biasP[nOff + tx * 8 + j];
    float* outP = (nBase < G4) ? xpF : xpB;
#pragma unroll
    for (int i = 0; i < 8; i++) {
        const int token = tokBase + ty * 8 + i;
        float* row = outP + (size_t)token * G4 + nOff + tx * 8;
        float4 v0, v1;
        v0.x = acc[i][0] + bj[0]; v0.y = acc[i][1] + bj[1];
        v0.z = acc[i][2] + bj[2]; v0.w = acc[i][3] + bj[3];
        v1.x = acc[i][4] + bj[4]; v1.y = acc[i][5] + bj[5];
        v1.z = acc[i][6] + bj[6]; v1.w = acc[i][7] + bj[7];
        *(float4*)row = v0;
        *(float4*)(row + 4) = v1;
    }
}

// ---------------- K3: clustered bi-LSTM, self-tagged flag-free sync ----------------
// Grid = 256 blocks: cluster = bid&31 (dir = cluster&1, smp = cluster>>1), cb = bid>>5.
// WG = 128 gate rows (4 gates x 32 cols) x 1 sample; 512 threads role (row, ks):
// row = (t>>6)*16 + (t&15), ks = (t>>4)&3 — 4-way k-split INSIDE the wave, so the
// partial combine is two __shfl_xor (no LDS, no barrier). 2 barriers per step.
// h published as (h_bits | (n+1)<<32) u64 relaxed agent atomics; consumers poll
// the tagged words with s_sleep backoff (prevents coherence-point congestion).
__global__ __launch_bounds__(LTHR) void lstm_kernel(
    const float* __restrict__ xpF, const float* __restrict__ xpB,
    const float* __restrict__ whhF, const float* __restrict__ whhB,
    const int* __restrict__ lengths,
    unsigned long long* __restrict__ hbuf,  // [2 par][32 cluster][256]
    float* __restrict__ hist)               // [2 dir][16 b][1024 t][256 j]
{
    const int bid     = blockIdx.x;
    const int cluster = bid & 31;
    const int cb      = bid >> 5;
    const int dir     = cluster & 1;
    const int smp     = cluster >> 1;      // 0..15
    const int t       = threadIdx.x;
    const int l       = t & 63;

    const float* xp  = dir ? xpB : xpF;
    const float* whh = dir ? whhB : whhF;

    // dot-phase role
    const int row  = (t >> 6) * 16 + (l & 15);   // 0..127 local gate row
    const int ks   = (l >> 4) & 3;               // k-quarter (intra-wave)
    const int gate = row >> 5;                   // 0..3 (i,f,g,o)
    const int col  = row & 31;
    const int grow = gate * HH + cb * CBC + col; // global gate row
    const bool ks0 = (ks == 0);
    // update role (t<32)
    const int jl = t & 31;

    __shared__ float h_stage[4][68];   // [ks][64 cols], padded: conflict-free 4-addr reads
    __shared__ float gates_s[128];     // [row]

    // W_hh slice -> registers: row grow, k in [ks*64, ks*64+64)
    float4 Wc[16];
    {
        const float4* wp = (const float4*)(whh + (size_t)grow * HH + ks * 64);
#pragma unroll
        for (int q = 0; q < 16; q++) Wc[q] = wp[q];
    }
    const int len = lengths[smp];
    float c_reg = 0.f, h_reg = 0.f;

    const unsigned long long* hRd0 = hbuf + cluster * CLW;
    const unsigned long long* hRd1 = hbuf + (size_t)NCLUST * CLW + cluster * CLW;
    unsigned long long* hWr0 = hbuf + cluster * CLW;
    unsigned long long* hWr1 = hbuf + (size_t)NCLUST * CLW + cluster * CLW;

    for (int n = 0; n < SS; ++n) {
        const int ts    = dir ? (SS - 1 - n) : n;
        const int par_r = (n + 1) & 1;       // parity holding h_{n-1}
        const int par_w = n & 1;

        // prefetch xp for this row (only the ks==0 lane consumes it)
        float xpv = 0.f;
        if (ks0) xpv = xp[((size_t)smp * SS + ts) * G4 + grow];

        // --- stage h_{n-1}: poll self-tagged words (t<256), backoff on miss ---
        if (t < 256) {
            const unsigned long long* src = (par_r ? hRd1 : hRd0) + t;
            unsigned long long v = __hip_atomic_load(src, __ATOMIC_RELAXED,
                                                     __HIP_MEMORY_SCOPE_AGENT);
            while ((unsigned int)(v >> 32) < (unsigned int)n) {
                __builtin_amdgcn_s_sleep(1);
                v = __hip_atomic_load(src, __ATOMIC_RELAXED,
                                      __HIP_MEMORY_SCOPE_AGENT);
            }
            h_stage[t >> 6][t & 63] = __builtin_bit_cast(float, (unsigned int)v);
        }
        __syncthreads();   // B1: h staged

        // --- dot: W (regs) x h (LDS, 4 conflict-free bcast addrs) + wave reduce ---
        float a = 0.f;
        {
            const float4* hp = (const float4*)&h_stage[ks][0];
#pragma unroll
            for (int q = 0; q < 16; q++) {
                const float4 w4 = Wc[q], h4 = hp[q];
                a = fmaf(w4.x, h4.x, a); a = fmaf(w4.y, h4.y, a);
                a = fmaf(w4.z, h4.z, a); a = fmaf(w4.w, h4.w, a);
            }
        }
        a += __shfl_xor(a, 16);
        a += __shfl_xor(a, 32);
        if (ks0) {
            const float gv = a + xpv;
            gates_s[row] = (gate == 2) ? tanhf(gv) : 1.f / (1.f + expf(-gv));
        }
        __syncthreads();   // B2: gates ready (also: h_stage reads done)

        // --- state update (32 cells, t<32) + tagged publish ---
        if (t < 32) {
            const float iv = gates_s[jl];
            const float fv = gates_s[32 + jl];
            const float gg = gates_s[64 + jl];
            const float ov = gates_s[96 + jl];
            const float cn = fmaf(fv, c_reg, iv * gg);
            const float hn = ov * tanhf(cn);
            const bool m = (ts < len);
            if (m) { c_reg = cn; h_reg = hn; }
            // self-tagged publish: (h bits | epoch n+1) — single 8B atomic store
            const unsigned long long val =
                (unsigned long long)__builtin_bit_cast(unsigned int, h_reg)
                | ((unsigned long long)(unsigned int)(n + 1) << 32);
            __hip_atomic_store((par_w ? hWr1 : hWr0) + cb * CBC + jl, val,
                               __ATOMIC_RELAXED, __HIP_MEMORY_SCOPE_AGENT);
            // history (read by out_kernel after kernel end) — off critical path
            __builtin_nontemporal_store(m ? h_reg : 0.f,
                hist + (((size_t)dir * BB + smp) * SS + ts) * HH + cb * CBC + jl);
        }
        // no trailing barrier: next-step writes fenced by B1/B2 pattern
    }
}

// ---------------- K4: gate dot + sigmoid + per-row exact top-k ranks ----------------
__global__ void out_kernel(const float* __restrict__ hist, const float* __restrict__ zw,
                           const float* __restrict__ zb, const int* __restrict__ lengths,
                           float* __restrict__ zout)
{
    const int b = blockIdx.x;
    const int t = threadIdx.x;
    __shared__ float probs[SS];
    __shared__ float zwsh[2 * HH];
    __shared__ int lsh;
    zwsh[t] = zw[t];
    zwsh[HH + t] = zw[HH + t];
    if (t == 0) lsh = lengths[b];
    __syncthreads();
    const int len = lsh;
    const float zbv = zb[0];

    for (int s = t; s < SS; s += 256) {
        const float4* hf  = (const float4*)(hist + ((size_t)b * SS + s) * HH);
        const float4* hb2 = (const float4*)(hist + (((size_t)BB + b) * SS + s) * HH);
        const float4* z0 = (const float4*)zwsh;
        const float4* z1 = (const float4*)(zwsh + HH);
        float acc = 0.f;
#pragma unroll 8
        for (int q = 0; q < HH / 4; q++) {
            const float4 h = hf[q], zv = z0[q];
            acc = fmaf(h.x, zv.x, acc); acc = fmaf(h.y, zv.y, acc);
            acc = fmaf(h.z, zv.z, acc); acc = fmaf(h.w, zv.w, acc);
        }
#pragma unroll 8
        for (int q = 0; q < HH / 4; q++) {
            const float4 h = hb2[q], zv = z1[q];
            acc = fmaf(h.x, zv.x, acc); acc = fmaf(h.y, zv.y, acc);
            acc = fmaf(h.z, zv.z, acc); acc = fmaf(h.w, zv.w, acc);
        }
        const float d = acc + zbv;
        probs[s] = (s < len) ? 1.f / (1.f + expf(-d)) : 0.f;
    }
    __syncthreads();

    const int kb = (int)rintf(0.1f * (float)len);  // jnp.round = half-even
    for (int s = t; s < SS; s += 256) {
        const float p = probs[s];
        int rank = 0;
        for (int j = 0; j < SS; j++) {
            const float pj = probs[j];
            rank += (pj > p) ? 1 : 0;
            rank += ((pj == p) && (j < s)) ? 1 : 0;
        }
        zout[b * SS + s] = (s < len && rank < kb) ? 1.f : 0.f;
    }
}

// ---------------- launch ----------------
extern "C" void kernel_launch(void* const* d_in, const int* in_sizes, int n_in,
                              void* d_out, int out_size, void* d_ws, size_t ws_size,
                              hipStream_t stream)
{
    (void)in_sizes; (void)n_in; (void)out_size; (void)ws_size;
    const int*   x    = (const int*)d_in[0];
    const void*  mask = d_in[1];
    const float* emb  = (const float*)d_in[2];
    const float* wihf = (const float*)d_in[3];
    const float* whhf = (const float*)d_in[4];
    const float* bf   = (const float*)d_in[5];
    const float* wihb = (const float*)d_in[6];
    const float* whhb = (const float*)d_in[7];
    const float* bb   = (const float*)d_in[8];
    const float* zw   = (const float*)d_in[9];
    const float* zb   = (const float*)d_in[10];
    float* zout = (float*)d_out;

    char* ws = (char*)d_ws;
    unsigned long long* hbuf = (unsigned long long*)(ws + HBUF_OFF);
    int*   lengths           = (int*)(ws + LEN_OFF);
    float* hist              = (float*)(ws + HIST_OFF);
    float* xpF               = (float*)(ws + XPF_OFF);
    float* xpB               = (float*)(ws + XPB_OFF);

    // zero BOTH parities of the tagged h buffer (epoch 0, h = 0). The 0xAA
    // poison would satisfy the epoch>=n poll with garbage — correctness-critical.
    hipMemsetAsync(ws, 0, HBUF_BYTES, stream);

    len_kernel<<<BB, 256, 0, stream>>>(mask, lengths);
    xp_gemm<<<dim3((BB * SS) / GB_BM, (2 * G4) / GB_BN), 256, 0, stream>>>(
        x, emb, wihf, bf, wihb, bb, xpF, xpB);
    lstm_kernel<<<NCB * NCLUST, LTHR, 0, stream>>>(xpF, xpB, whhf, whhb, lengths,
                                                   hbuf, hist);
    out_kernel<<<BB, 256, 0, stream>>>(hist, zw, zb, lengths, zout);
}